// Round 1
// baseline (218.797 us; speedup 1.0000x reference)
//
#include <hip/hip_runtime.h>
#include <hip/hip_cooperative_groups.h>
#include <cstdint>
#include <cstddef>

namespace cg = cooperative_groups;

#define BN 32
#define PN 1000
#define GN 24
#define NPTSN 72
#define DNN 78
#define CHN 16         // pred chunks in phase A
#define PPC 63         // preds per chunk (16*63 >= 1000)
#define NBLK (CHN*BN)  // 512 blocks, 2/CU guaranteed by launch_bounds(256,2)
#define EPSF 1e-8f
#define INF __builtin_inff()

// ---- workspace layout (units of 4 bytes) ----
#define OFF_DIST  0
#define OFF_LIOU  768000
#define OFF_COST  1536000   // float cost matrix [b][g][p], +INF where unwritten
#define OFF_PX    2304000
#define OFF_PY    2336000
#define OFF_PTH   2368000
#define OFF_CLS   2400000
#define OFF_PART  2432000   // partial maxima [b][16][3]
#define OFF_CNT   2433536   // match count (int)   [b][p]
#define OFF_SELG  2465536   // unique selector g   [b][p]
// total ~2.5M floats = 10 MB (ws is 256 MB)

// ---------- helpers ----------
__device__ __forceinline__ unsigned ordf(float f) {
  unsigned u = __float_as_uint(f);
  return (u & 0x80000000u) ? ~u : (u | 0x80000000u);
}
__device__ __forceinline__ float unordf(unsigned u) {
  return __uint_as_float((u & 0x80000000u) ? (u ^ 0x80000000u) : ~u);
}
__device__ __forceinline__ unsigned long long shfl_xor_u64(unsigned long long v, int m) {
  int lo = __shfl_xor((int)(unsigned)v, m);
  int hi = __shfl_xor((int)(unsigned)(v >> 32), m);
  return (((unsigned long long)(unsigned)hi) << 32) | (unsigned)lo;
}

// masks may arrive as int32, uint8, or float32. mask[b][0] is always true
// (num_gt >= 1), which makes the layouts distinguishable.
// Must be called by ALL threads of the block (contains __syncthreads).
__device__ int detect_mask_layout(const void* masks, int* sflag) {
  const unsigned* mw = (const unsigned*)masks;
  if (mw[0] == 0x3f800000u) return 2;   // float32 1.0f
  if (threadIdx.x == 0) *sflag = 0;
  __syncthreads();
  const unsigned char* mb = (const unsigned char*)masks;
  int local = 0;
  for (int i = threadIdx.x; i < BN * GN; i += blockDim.x)
    if ((i & 3) != 0 && mb[i] != 0) local = 1;
  if (local) atomicOr(sflag, 1);
  __syncthreads();
  return (*sflag) ? 1 : 0;
}
__device__ __forceinline__ int mask_val(const void* masks, int layout, int idx) {
  if (layout == 2) return ((const float*)masks)[idx] != 0.0f;
  if (layout == 1) return ((const unsigned char*)masks)[idx] != 0;
  return ((const int*)masks)[idx] != 0;
}

// ================== fused cooperative kernel ==================
__global__ __launch_bounds__(256, 2) void clr_fused(
    const float* __restrict__ preds, const float* __restrict__ targets,
    const void* __restrict__ masks, const int* __restrict__ imw,
    const int* __restrict__ imh, float* __restrict__ ws, int* __restrict__ out)
{
  const int bx = blockIdx.x;           // 0..511
  const int b  = bx >> 4;              // batch
  const int c  = bx & 15;              // pred chunk
  const int tid = threadIdx.x;
  const int lane = tid & 63;
  const int gq = __builtin_amdgcn_readfirstlane(tid >> 6);  // uniform wave id
  const float wf  = (float)imw[0];
  const float wm1 = wf - 1.0f, hm1 = (float)imh[0] - 1.0f;
  int* wsi = (int*)ws;

  // ---------- zone init (consumed only after grid.sync) ----------
  {
    int gid = bx * 256 + tid;
    if (gid < BN * PN) {
      wsi[OFF_CNT + gid]  = 0;
      wsi[OFF_SELG + gid] = 0x7fffffff;
    }
    for (int k = gid; k < BN * GN * PN; k += NBLK * 256)
      ws[OFF_COST + k] = INF;
  }

  __shared__ float svl[GN], snv[GN], sgx[GN], sgy[GN], sgth[GN];
  __shared__ int sgm[GN];
  __shared__ int sng, sflag;
  __shared__ float red[4][3];
  __shared__ unsigned long long ctop[4][4], ltop[4][4];

  const int mlay = detect_mask_layout(masks, &sflag);

  // ---------- per-b target summary (small; 24 threads) ----------
  if (tid < GN) {
    const float* tr = targets + (size_t)(b * GN + tid) * DNN;
    float cnt = 0.0f;
    for (int j = 0; j < NPTSN; j++) {
      float ts = tr[6 + j] * wm1;               // reference-exact validity
      cnt += (ts >= 0.0f && ts < wf) ? 1.0f : 0.0f;
    }
    snv[tid] = cnt;               // unclipped (liou)
    svl[tid] = fmaxf(cnt, 1.0f);  // clipped (dist)
    sgx[tid]  = tr[2] * hm1;
    sgy[tid]  = tr[3] * wm1;
    sgth[tid] = tr[4] * 180.0f;
    sgm[tid] = mask_val(masks, mlay, b * GN + tid);
  }
  __syncthreads();
  if (tid == 0) {
    int n = 0;
    for (int g = 0; g < GN; g++) n += sgm[g];
    sng = n;   // mask is a prefix (arange < num_gt)
  }
  __syncthreads();
  const int ng = __builtin_amdgcn_readfirstlane(sng);

  // ---------- per-pred load (RAW point coords; wm1 factored out) ----------
  const int p = c * PPC + lane;
  const bool active = (lane < PPC) && (p < PN);
  float pp[NPTSN];
  float ppx = 0.f, ppy = 0.f, ppth = 0.f;
  if (active) {
    const float* row = preds + (size_t)(b * PN + p) * DNN;
    const float2* r2 = (const float2*)row;     // 8B-aligned (78 floats/row)
    float2 c23 = r2[1], c45 = r2[2];
    ppx = c23.x * hm1; ppy = c23.y * wm1; ppth = c45.x * 180.0f;
    #pragma unroll
    for (int j = 0; j < NPTSN / 2; j++) {
      float2 v = r2[3 + j];
      pp[2 * j]     = v.x;        // raw (unscaled)
      pp[2 * j + 1] = v.y;
    }
    if (gq == 0) {
      float2 c01 = r2[0];
      float m = fmaxf(c01.x, c01.y);
      float e0 = expf(c01.x - m), e1 = expf(c01.y - m);
      float p1 = fmaxf(e1 / (e0 + e1), EPSF);
      ws[OFF_PX  + b * PN + p] = ppx;
      ws[OFF_PY  + b * PN + p] = ppy;
      ws[OFF_PTH + b * PN + p] = ppth;
      ws[OFF_CLS + b * PN + p] = -logf(p1);
    }
  } else {
    #pragma unroll
    for (int j = 0; j < NPTSN; j++) pp[j] = 0.0f;
  }

  // ---------- phase A heavy loop: targets via wave-uniform scalar loads ----
  float mxd = -INF, mxs = -INF, mxt = -INF;
  for (int i = 0; i < 6; i++) {
    const int g = gq + 4 * i;             // wave-uniform, balanced over prefix
    if (g >= ng) break;
    const float NV = snv[g];
    const float* tr6 = targets + (size_t)(b * GN + g) * DNN + 6;  // uniform
    float S0 = 0.f, S1 = 0.f, S2 = 0.f, S3 = 0.f;
    if (NV == (float)NPTSN) {
      // fast path: all points valid -> 2 VALU/elem, zero LDS
      #pragma unroll
      for (int jj = 0; jj < NPTSN; jj += 4) {
        S0 += fabsf(pp[jj + 0] - tr6[jj + 0]);
        S1 += fabsf(pp[jj + 1] - tr6[jj + 1]);
        S2 += fabsf(pp[jj + 2] - tr6[jj + 2]);
        S3 += fabsf(pp[jj + 3] - tr6[jj + 3]);
      }
    } else {
      #pragma unroll
      for (int jj = 0; jj < NPTSN; jj += 4) {
        float t0 = tr6[jj + 0], t1 = tr6[jj + 1];
        float t2 = tr6[jj + 2], t3 = tr6[jj + 3];
        float v0 = t0 * wm1, v1 = t1 * wm1, v2 = t2 * wm1, v3 = t3 * wm1;
        S0 += (v0 >= 0.0f && v0 < wf) ? fabsf(pp[jj + 0] - t0) : 0.0f;
        S1 += (v1 >= 0.0f && v1 < wf) ? fabsf(pp[jj + 1] - t1) : 0.0f;
        S2 += (v2 >= 0.0f && v2 < wf) ? fabsf(pp[jj + 2] - t2) : 0.0f;
        S3 += (v3 >= 0.0f && v3 < wf) ? fabsf(pp[jj + 3] - t3) : 0.0f;
      }
    }
    float S = ((S0 + S1) + (S2 + S3)) * wm1;   // scale once: wm1*|a-b| == |a*wm1 - b*wm1|
    float dist = S / svl[g];
    float liou = (30.0f * NV - S) / (30.0f * NV + S + 1e-9f);
    float dx = ppx - sgx[g], dy = ppy - sgy[g];
    float sd = sqrtf(dx * dx + dy * dy);
    float td = fabsf(ppth - sgth[g]);
    if (active) {
      size_t o = (size_t)(b * GN + g) * PN + p;
      ws[OFF_DIST + o] = dist;
      ws[OFF_LIOU + o] = liou;
      mxd = fmaxf(mxd, dist);
      mxs = fmaxf(mxs, sd);
      mxt = fmaxf(mxt, td);
    }
  }

  #pragma unroll
  for (int off = 32; off; off >>= 1) {
    mxd = fmaxf(mxd, __shfl_xor(mxd, off));
    mxs = fmaxf(mxs, __shfl_xor(mxs, off));
    mxt = fmaxf(mxt, __shfl_xor(mxt, off));
  }
  if (lane == 0) { red[gq][0] = mxd; red[gq][1] = mxs; red[gq][2] = mxt; }
  __syncthreads();
  if (tid == 0) {
    float a = red[0][0], s = red[0][1], t = red[0][2];
    for (int i = 1; i < 4; i++) {
      a = fmaxf(a, red[i][0]);
      s = fmaxf(s, red[i][1]);
      t = fmaxf(t, red[i][2]);
    }
    ws[OFF_PART + bx * 3 + 0] = a;
    ws[OFF_PART + bx * 3 + 1] = s;
    ws[OFF_PART + bx * 3 + 2] = t;
  }

  // ================== phase boundary ==================
  cg::this_grid().sync();

  // ---------- phase B: per (b,g) cost column, top-4 cost / top-4 liou ------
  for (int task = bx; task < BN * GN; task += NBLK) {
    const int b2 = task / GN;
    const int g2 = task - b2 * GN;
    if (mask_val(masks, mlay, task)) {
      const int wv = tid >> 6;
      float Md = -INF, Ms = -INF, Mt = -INF;
      for (int c2 = 0; c2 < CHN; c2++) {
        Md = fmaxf(Md, ws[OFF_PART + (b2 * CHN + c2) * 3 + 0]);
        Ms = fmaxf(Ms, ws[OFF_PART + (b2 * CHN + c2) * 3 + 1]);
        Mt = fmaxf(Mt, ws[OFF_PART + (b2 * CHN + c2) * 3 + 2]);
      }
      const float* tr = targets + (size_t)task * DNN;
      const float tx = tr[2] * hm1, ty = tr[3] * wm1, tth = tr[4] * 180.0f;
      const size_t dbase = (size_t)task * PN;

      unsigned long long ck[4], lk[4];
      #pragma unroll
      for (int i = 0; i < 4; i++) {
        int p2 = tid + i * 256;
        unsigned long long kc = ~0ull, kl = ~0ull;
        if (p2 < PN) {
          float dist = ws[OFF_DIST + dbase + p2];
          float liou = ws[OFF_LIOU + dbase + p2];
          float px  = ws[OFF_PX  + b2 * PN + p2];
          float py  = ws[OFF_PY  + b2 * PN + p2];
          float pth = ws[OFF_PTH + b2 * PN + p2];
          float cls = ws[OFF_CLS + b2 * PN + p2];
          float dsc = (1.0f - dist / (Md + EPSF)) + 0.01f;
          float dx = px - tx, dy = py - ty;
          float xsc = (1.0f - sqrtf(dx * dx + dy * dy) / (Ms + EPSF)) + 0.01f;
          float tsc = (1.0f - fabsf(pth - tth) / (Mt + EPSF)) + 0.01f;
          float r = (dsc * xsc) * tsc;
          float cost = -(r * r) * 3.0f + cls;
          ws[OFF_COST + dbase + p2] = cost;   // coalesced; replaces 400k atomicMin
          unsigned oc = ordf(cost);
          kc = (((unsigned long long)oc) << 32) | (unsigned)p2;
          kl = (((unsigned long long)(unsigned)(~ordf(liou))) << 32) | (unsigned)p2;
        }
        ck[i] = kc; lk[i] = kl;
      }

      #pragma unroll
      for (int pass = 0; pass < 4; pass++) {
        unsigned long long m = ck[0];
        #pragma unroll
        for (int i = 1; i < 4; i++) m = (ck[i] < m) ? ck[i] : m;
        #pragma unroll
        for (int off = 32; off; off >>= 1) {
          unsigned long long o = shfl_xor_u64(m, off);
          m = (o < m) ? o : m;
        }
        #pragma unroll
        for (int i = 0; i < 4; i++) if (ck[i] == m) ck[i] = ~0ull;
        if (lane == 0) ctop[wv][pass] = m;
      }
      #pragma unroll
      for (int pass = 0; pass < 4; pass++) {
        unsigned long long m = lk[0];
        #pragma unroll
        for (int i = 1; i < 4; i++) m = (lk[i] < m) ? lk[i] : m;
        #pragma unroll
        for (int off = 32; off; off >>= 1) {
          unsigned long long o = shfl_xor_u64(m, off);
          m = (o < m) ? o : m;
        }
        #pragma unroll
        for (int i = 0; i < 4; i++) if (lk[i] == m) lk[i] = ~0ull;
        if (lane == 0) ltop[wv][pass] = m;
      }
      __syncthreads();

      if (tid == 0) {
        unsigned long long c4[4] = {~0ull, ~0ull, ~0ull, ~0ull};
        unsigned long long l4[4] = {~0ull, ~0ull, ~0ull, ~0ull};
        for (int i = 0; i < 16; i++) {
          unsigned long long v = ctop[i >> 2][i & 3];
          for (int j = 0; j < 4; j++)
            if (v < c4[j]) { unsigned long long t = c4[j]; c4[j] = v; v = t; }
          v = ltop[i >> 2][i & 3];
          for (int j = 0; j < 4; j++)
            if (v < l4[j]) { unsigned long long t = l4[j]; l4[j] = v; v = t; }
        }
        // l4 ascending keys == liou descending values; sum like top_k
        float s = 0.0f;
        for (int j = 0; j < 4; j++) s += unordf(~(unsigned)(l4[j] >> 32));
        int k = (int)s;                 // trunc toward zero == astype(int32)
        if (k < 1) k = 1;
        if (k > 4) k = 4;
        for (int j = 0; j < k; j++) {
          int cand = (int)(unsigned)(c4[j] & 0xffffffffu);
          atomicAdd(&wsi[OFF_CNT + b2 * PN + cand], 1);
          atomicMin(&wsi[OFF_SELG + b2 * PN + cand], g2);
        }
      }
      __syncthreads();   // ctop/ltop reused by next task
    }
  }

  // ================== phase boundary ==================
  cg::this_grid().sync();

  // ---------- phase C: streaming finalize ----------
  {
    const int i = bx * 256 + tid;
    if (i < BN * PN) {
      int cnt = wsi[OFF_CNT + i];
      int matched = -1;
      if (cnt == 1) {
        matched = wsi[OFF_SELG + i];
      } else if (cnt > 1) {
        // argmin over g of cost (first g wins ties, == jnp.argmin)
        const int b3 = i / PN, p3 = i - b3 * PN;
        float best = INF; int bgm = -1;
        for (int g = 0; g < GN; g++) {
          float cst = ws[OFF_COST + ((size_t)(b3 * GN + g)) * PN + p3];
          if (cst < best) { best = cst; bgm = g; }
        }
        matched = bgm;
      }
      out[i] = (cnt > 0) ? 1 : 0;
      out[BN * PN + i] = matched;
    }
  }
}

extern "C" void kernel_launch(void* const* d_in, const int* in_sizes, int n_in,
                              void* d_out, int out_size, void* d_ws, size_t ws_size,
                              hipStream_t stream) {
  const float* preds   = (const float*)d_in[0];
  const float* targets = (const float*)d_in[1];
  const void*  masks   = (const void*)d_in[2];
  const int*   imw     = (const int*)d_in[3];
  const int*   imh     = (const int*)d_in[4];
  float* ws = (float*)d_ws;
  int*   out = (int*)d_out;

  void* args[7] = { (void*)&preds, (void*)&targets, (void*)&masks,
                    (void*)&imw, (void*)&imh, (void*)&ws, (void*)&out };
  hipLaunchCooperativeKernel((const void*)clr_fused, dim3(NBLK), dim3(256),
                             args, 0, stream);
}

// Round 2
// 176.906 us; speedup vs baseline: 1.2368x; 1.2368x over previous
//
#include <hip/hip_runtime.h>
#include <hip/hip_cooperative_groups.h>
#include <cstdint>
#include <cstddef>

namespace cg = cooperative_groups;

#define BN 32
#define PN 1000
#define GN 24
#define NPTSN 72
#define DNN 78
#define CHN 16         // pred chunks in K1
#define PPC 63         // preds per chunk (16*63 >= 1000)
#define EPSF 1e-8f
#define INF __builtin_inff()

// ---- workspace layout (units of 4 bytes) ----
#define OFF_DIST  0
#define OFF_LIOU  768000
#define OFF_COST  1536000   // float cost matrix [b][g][p], +INF where unwritten
#define OFF_PX    2304000
#define OFF_PY    2336000
#define OFF_PTH   2368000
#define OFF_CLS   2400000
#define OFF_PART  2432000   // partial maxima [b][16][3]
#define OFF_CNT   2433536   // match count (int)   [b][p]
#define OFF_SELG  2465536   // unique selector g   [b][p]
// total ~2.5M floats = 10 MB (ws is 256 MB)

// ---------- helpers ----------
__device__ __forceinline__ unsigned ordf(float f) {
  unsigned u = __float_as_uint(f);
  return (u & 0x80000000u) ? ~u : (u | 0x80000000u);
}
__device__ __forceinline__ float unordf(unsigned u) {
  return __uint_as_float((u & 0x80000000u) ? (u ^ 0x80000000u) : ~u);
}
__device__ __forceinline__ unsigned long long shfl_xor_u64(unsigned long long v, int m) {
  int lo = __shfl_xor((int)(unsigned)v, m);
  int hi = __shfl_xor((int)(unsigned)(v >> 32), m);
  return (((unsigned long long)(unsigned)hi) << 32) | (unsigned)lo;
}

// masks may arrive as int32, uint8, or float32. mask[b][0] is always true
// (num_gt >= 1), which makes the layouts distinguishable.
// Must be called by ALL threads of the block (contains __syncthreads).
__device__ int detect_mask_layout(const void* masks, int* sflag) {
  const unsigned* mw = (const unsigned*)masks;
  if (mw[0] == 0x3f800000u) return 2;   // float32 1.0f
  if (threadIdx.x == 0) *sflag = 0;
  __syncthreads();
  const unsigned char* mb = (const unsigned char*)masks;
  int local = 0;
  for (int i = threadIdx.x; i < BN * GN; i += blockDim.x)
    if ((i & 3) != 0 && mb[i] != 0) local = 1;
  if (local) atomicOr(sflag, 1);
  __syncthreads();
  return (*sflag) ? 1 : 0;
}
__device__ __forceinline__ int mask_val(const void* masks, int layout, int idx) {
  if (layout == 2) return ((const float*)masks)[idx] != 0.0f;
  if (layout == 1) return ((const unsigned char*)masks)[idx] != 0;
  return ((const int*)masks)[idx] != 0;
}

// ---------- K1: zone init + per-block target prep (LDS) + heavy (p,g) loop ----------
__global__ __launch_bounds__(256) void clr_k1(
    const float* __restrict__ preds, const float* __restrict__ targets,
    const void* __restrict__ masks, const int* __restrict__ imw,
    const int* __restrict__ imh, float* __restrict__ ws)
{
  const int b = blockIdx.y, c = blockIdx.x;
  const int tid = threadIdx.x;
  const int lane = tid & 63;
  const int gq = __builtin_amdgcn_readfirstlane(tid >> 6);  // uniform wave id
  const float wf = (float)imw[0];
  const float wm1 = wf - 1.0f, hm1 = (float)imh[0] - 1.0f;

  // ---- zone init (nothing reads these until K2, a later kernel) ----
  {
    int gid = (b * CHN + c) * 256 + tid;
    int* wsi = (int*)ws;
    if (gid < BN * PN) {
      wsi[OFF_CNT + gid] = 0;
      wsi[OFF_SELG + gid] = 0x7fffffff;
    }
    for (int k = gid; k < BN * GN * PN; k += CHN * BN * 256)
      ws[OFF_COST + k] = INF;
  }

  // ---- per-block target prep into LDS ----
  __shared__ __align__(16) float sts[GN * NPTSN];
  __shared__ __align__(16) float stw[GN * NPTSN];
  __shared__ float svl[GN], snv[GN], sgx[GN], sgy[GN], sgth[GN];
  __shared__ int sgm[GN];
  __shared__ int sng;
  __shared__ int sflag;
  __shared__ float red[4][3];

  const int mlay = detect_mask_layout(masks, &sflag);

  for (int idx = tid; idx < GN * NPTSN; idx += 256) {
    int g = idx / NPTSN, j = idx - g * NPTSN;
    float t = targets[(size_t)(b * GN + g) * DNN + 6 + j] * wm1;
    sts[idx] = t;
    stw[idx] = (t >= 0.0f && t < wf) ? 1.0f : 0.0f;
  }
  __syncthreads();
  if (tid < GN) {
    float cnt = 0.0f;
    for (int j = 0; j < NPTSN; j++) cnt += stw[tid * NPTSN + j];
    snv[tid] = cnt;               // unclipped (liou)
    svl[tid] = fmaxf(cnt, 1.0f);  // clipped (dist)
    const float* tr = targets + (size_t)(b * GN + tid) * DNN;
    sgx[tid]  = tr[2] * hm1;
    sgy[tid]  = tr[3] * wm1;
    sgth[tid] = tr[4] * 180.0f;
    sgm[tid] = mask_val(masks, mlay, b * GN + tid);
  }
  __syncthreads();
  if (tid == 0) {
    int n = 0;
    for (int g = 0; g < GN; g++) n += sgm[g];
    sng = n;   // mask is a prefix (arange < num_gt)
  }
  __syncthreads();
  const int ng = sng;

  // ---- per-pred load ----
  const int p = c * PPC + lane;
  const bool active = (lane < PPC) && (p < PN);
  float pp[NPTSN];
  float ppx = 0.f, ppy = 0.f, ppth = 0.f;
  if (active) {
    const float* row = preds + (size_t)(b * PN + p) * DNN;
    const float2* r2 = (const float2*)row;     // 8B-aligned (78 floats/row)
    float2 c23 = r2[1], c45 = r2[2];
    ppx = c23.x * hm1; ppy = c23.y * wm1; ppth = c45.x * 180.0f;
    #pragma unroll
    for (int j = 0; j < NPTSN / 2; j++) {
      float2 v = r2[3 + j];
      pp[2 * j]     = v.x * wm1;
      pp[2 * j + 1] = v.y * wm1;
    }
    if (gq == 0) {
      float2 c01 = r2[0];
      float m = fmaxf(c01.x, c01.y);
      float e0 = expf(c01.x - m), e1 = expf(c01.y - m);
      float p1 = fmaxf(e1 / (e0 + e1), EPSF);
      ws[OFF_PX  + b * PN + p] = ppx;
      ws[OFF_PY  + b * PN + p] = ppy;
      ws[OFF_PTH + b * PN + p] = ppth;
      ws[OFF_CLS + b * PN + p] = -logf(p1);
    }
  } else {
    #pragma unroll
    for (int j = 0; j < NPTSN; j++) pp[j] = 0.0f;
  }

  // ---- heavy loop: g interleaved across waves for balance (g = gq + 4i) ----
  float mxd = -INF, mxs = -INF, mxt = -INF;
  for (int i = 0; i < 6; i++) {
    const int g = gq + 4 * i;             // wave-uniform, balanced over masked prefix
    if (g >= ng) break;
    const float NV = snv[g];
    const float4* t4 = (const float4*)&sts[g * NPTSN];  // broadcast ds_read_b128
    float S0 = 0.f, S1 = 0.f, S2 = 0.f, S3 = 0.f;
    if (NV == (float)NPTSN) {
      // fast path: all points valid -> no stw reads, no weight multiply.
      // Bit-exact vs weighted path (elides *1.0f), same accumulation order.
      #pragma unroll
      for (int jj = 0; jj < NPTSN / 4; jj++) {
        float4 t = t4[jj];
        S0 += fabsf(pp[4 * jj + 0] - t.x);
        S1 += fabsf(pp[4 * jj + 1] - t.y);
        S2 += fabsf(pp[4 * jj + 2] - t.z);
        S3 += fabsf(pp[4 * jj + 3] - t.w);
      }
    } else {
      const float4* w4 = (const float4*)&stw[g * NPTSN];
      #pragma unroll
      for (int jj = 0; jj < NPTSN / 4; jj++) {
        float4 t = t4[jj], w = w4[jj];
        S0 += w.x * fabsf(pp[4 * jj + 0] - t.x);
        S1 += w.y * fabsf(pp[4 * jj + 1] - t.y);
        S2 += w.z * fabsf(pp[4 * jj + 2] - t.z);
        S3 += w.w * fabsf(pp[4 * jj + 3] - t.w);
      }
    }
    float S = (S0 + S1) + (S2 + S3);
    const float VL = svl[g];
    float dist = S / VL;
    float liou = (30.0f * NV - S) / (30.0f * NV + S + 1e-9f);
    float dx = ppx - sgx[g], dy = ppy - sgy[g];
    float sd = sqrtf(dx * dx + dy * dy);
    float td = fabsf(ppth - sgth[g]);
    if (active) {
      size_t o = (size_t)(b * GN + g) * PN + p;
      ws[OFF_DIST + o] = dist;
      ws[OFF_LIOU + o] = liou;
      mxd = fmaxf(mxd, dist);
      mxs = fmaxf(mxs, sd);
      mxt = fmaxf(mxt, td);
    }
  }

  #pragma unroll
  for (int off = 32; off; off >>= 1) {
    mxd = fmaxf(mxd, __shfl_xor(mxd, off));
    mxs = fmaxf(mxs, __shfl_xor(mxs, off));
    mxt = fmaxf(mxt, __shfl_xor(mxt, off));
  }
  if (lane == 0) { red[gq][0] = mxd; red[gq][1] = mxs; red[gq][2] = mxt; }
  __syncthreads();
  if (tid == 0) {
    float a = red[0][0], s = red[0][1], t = red[0][2];
    for (int i = 1; i < 4; i++) {
      a = fmaxf(a, red[i][0]);
      s = fmaxf(s, red[i][1]);
      t = fmaxf(t, red[i][2]);
    }
    ws[OFF_PART + (b * CHN + c) * 3 + 0] = a;
    ws[OFF_PART + (b * CHN + c) * 3 + 1] = s;
    ws[OFF_PART + (b * CHN + c) * 3 + 2] = t;
  }
}

// ---------- K2 (cooperative): per (b,g) cost + top-4s + ks; sync; finalize ----------
__global__ __launch_bounds__(256, 3) void clr_k2(
    const float* __restrict__ targets, const void* __restrict__ masks,
    const int* __restrict__ imw, const int* __restrict__ imh,
    float* __restrict__ ws, int* __restrict__ out)
{
  const int g = blockIdx.x, b = blockIdx.y;   // grid = (GN, BN) = 768 blocks
  const int bg = b * GN + g;
  const int tid = threadIdx.x;
  const int lane = tid & 63;
  const int wv = tid >> 6;
  int* wsi = (int*)ws;

  __shared__ int sflag;
  __shared__ unsigned long long ctop[4][4], ltop[4][4];
  const int mlay = detect_mask_layout(masks, &sflag);   // all threads (has barrier)

  // ---- phase B: only masked columns contribute (no early return: grid.sync below)
  if (mask_val(masks, mlay, bg)) {
    const float hm1 = (float)imh[0] - 1.0f;
    const float wm1 = (float)imw[0] - 1.0f;

    float Md = -INF, Ms = -INF, Mt = -INF;
    for (int c2 = 0; c2 < CHN; c2++) {
      Md = fmaxf(Md, ws[OFF_PART + (b * CHN + c2) * 3 + 0]);
      Ms = fmaxf(Ms, ws[OFF_PART + (b * CHN + c2) * 3 + 1]);
      Mt = fmaxf(Mt, ws[OFF_PART + (b * CHN + c2) * 3 + 2]);
    }
    const float* tr = targets + (size_t)bg * DNN;
    const float tx = tr[2] * hm1, ty = tr[3] * wm1, tth = tr[4] * 180.0f;
    const size_t dbase = (size_t)bg * PN;

    unsigned long long ck[4], lk[4];
    #pragma unroll
    for (int i = 0; i < 4; i++) {
      int p = tid + i * 256;
      unsigned long long kc = ~0ull, kl = ~0ull;
      if (p < PN) {
        float dist = ws[OFF_DIST + dbase + p];
        float liou = ws[OFF_LIOU + dbase + p];
        float px  = ws[OFF_PX  + b * PN + p];
        float py  = ws[OFF_PY  + b * PN + p];
        float pth = ws[OFF_PTH + b * PN + p];
        float cls = ws[OFF_CLS + b * PN + p];
        float dsc = (1.0f - dist / (Md + EPSF)) + 0.01f;
        float dx = px - tx, dy = py - ty;
        float xsc = (1.0f - sqrtf(dx * dx + dy * dy) / (Ms + EPSF)) + 0.01f;
        float tsc = (1.0f - fabsf(pth - tth) / (Mt + EPSF)) + 0.01f;
        float r = (dsc * xsc) * tsc;
        float cost = -(r * r) * 3.0f + cls;
        ws[OFF_COST + dbase + p] = cost;   // coalesced; replaces u64 atomicMin
        unsigned oc = ordf(cost);
        kc = (((unsigned long long)oc) << 32) | (unsigned)p;
        kl = (((unsigned long long)(unsigned)(~ordf(liou))) << 32) | (unsigned)p;
      }
      ck[i] = kc; lk[i] = kl;
    }

    #pragma unroll
    for (int pass = 0; pass < 4; pass++) {
      unsigned long long m = ck[0];
      #pragma unroll
      for (int i = 1; i < 4; i++) m = (ck[i] < m) ? ck[i] : m;
      #pragma unroll
      for (int off = 32; off; off >>= 1) {
        unsigned long long o = shfl_xor_u64(m, off);
        m = (o < m) ? o : m;
      }
      #pragma unroll
      for (int i = 0; i < 4; i++) if (ck[i] == m) ck[i] = ~0ull;
      if (lane == 0) ctop[wv][pass] = m;
    }
    #pragma unroll
    for (int pass = 0; pass < 4; pass++) {
      unsigned long long m = lk[0];
      #pragma unroll
      for (int i = 1; i < 4; i++) m = (lk[i] < m) ? lk[i] : m;
      #pragma unroll
      for (int off = 32; off; off >>= 1) {
        unsigned long long o = shfl_xor_u64(m, off);
        m = (o < m) ? o : m;
      }
      #pragma unroll
      for (int i = 0; i < 4; i++) if (lk[i] == m) lk[i] = ~0ull;
      if (lane == 0) ltop[wv][pass] = m;
    }
    __syncthreads();

    if (tid == 0) {
      unsigned long long c4[4] = {~0ull, ~0ull, ~0ull, ~0ull};
      unsigned long long l4[4] = {~0ull, ~0ull, ~0ull, ~0ull};
      for (int i = 0; i < 16; i++) {
        unsigned long long v = ctop[i >> 2][i & 3];
        for (int j = 0; j < 4; j++)
          if (v < c4[j]) { unsigned long long t = c4[j]; c4[j] = v; v = t; }
        v = ltop[i >> 2][i & 3];
        for (int j = 0; j < 4; j++)
          if (v < l4[j]) { unsigned long long t = l4[j]; l4[j] = v; v = t; }
      }
      // l4 ascending keys == liou descending values; sum in that order like top_k
      float s = 0.0f;
      for (int j = 0; j < 4; j++) s += unordf(~(unsigned)(l4[j] >> 32));
      int k = (int)s;                 // trunc toward zero == astype(int32)
      if (k < 1) k = 1;
      if (k > 4) k = 4;
      for (int j = 0; j < k; j++) {
        int cand = (int)(unsigned)(c4[j] & 0xffffffffu);
        atomicAdd(&wsi[OFF_CNT + b * PN + cand], 1);
        atomicMin(&wsi[OFF_SELG + b * PN + cand], g);
      }
    }
  }

  // ================== phase boundary ==================
  cg::this_grid().sync();

  // ---- phase C: streaming finalize (768*256 threads cover 32000 items) ----
  {
    const int i = bg * 256 + tid;
    if (i < BN * PN) {
      int cnt = wsi[OFF_CNT + i];
      int matched = -1;
      if (cnt == 1) {
        matched = wsi[OFF_SELG + i];
      } else if (cnt > 1) {
        // argmin over g of cost (first g wins ties, == jnp.argmin)
        const int b3 = i / PN, p3 = i - b3 * PN;
        float best = INF; int bgm = -1;
        for (int gg = 0; gg < GN; gg++) {
          float cst = ws[OFF_COST + ((size_t)(b3 * GN + gg)) * PN + p3];
          if (cst < best) { best = cst; bgm = gg; }
        }
        matched = bgm;
      }
      out[i] = (cnt > 0) ? 1 : 0;
      out[BN * PN + i] = matched;
    }
  }
}

extern "C" void kernel_launch(void* const* d_in, const int* in_sizes, int n_in,
                              void* d_out, int out_size, void* d_ws, size_t ws_size,
                              hipStream_t stream) {
  const float* preds   = (const float*)d_in[0];
  const float* targets = (const float*)d_in[1];
  const void*  masks   = (const void*)d_in[2];
  const int*   imw     = (const int*)d_in[3];
  const int*   imh     = (const int*)d_in[4];
  float* ws = (float*)d_ws;
  int*   out = (int*)d_out;

  hipLaunchKernelGGL(clr_k1, dim3(CHN, BN), dim3(256), 0, stream,
                     preds, targets, masks, imw, imh, ws);

  void* args[6] = { (void*)&targets, (void*)&masks, (void*)&imw,
                    (void*)&imh, (void*)&ws, (void*)&out };
  hipLaunchCooperativeKernel((const void*)clr_k2, dim3(GN, BN), dim3(256),
                             args, 0, stream);
}

// Round 3
// 152.325 us; speedup vs baseline: 1.4364x; 1.1614x over previous
//
#include <hip/hip_runtime.h>
#include <cstdint>
#include <cstddef>

#define BN 32
#define PN 1000
#define GN 24
#define NPTSN 72
#define DNN 78
#define CHN 16         // pred chunks in K1
#define PPC 63         // preds per chunk (16*63 >= 1000)
#define EPSF 1e-8f
#define INF __builtin_inff()

// ---- workspace layout (units of 4 bytes) ----
#define OFF_DIST  0
#define OFF_LIOU  768000
#define OFF_PX    1536000
#define OFF_PY    1568000
#define OFF_PTH   1600000
#define OFF_CLS   1632000
#define OFF_PART  1664000   // partial maxima [b][16][3]
#define OFF_CNT   1665536   // match count (int)   [b][p]
#define OFF_SELG  1697536   // unique selector g   [b][p]
#define OFF_BEST  1729536   // u64 (ordcost<<32|g) [b][p]  (even -> 8B aligned)
#define OFF_BDONE 1793536   // per-b arrival counter [b]
// total ~1.79M floats = 7.2 MB (ws is 256 MB)

// ---------- helpers ----------
__device__ __forceinline__ unsigned ordf(float f) {
  unsigned u = __float_as_uint(f);
  return (u & 0x80000000u) ? ~u : (u | 0x80000000u);
}
__device__ __forceinline__ float unordf(unsigned u) {
  return __uint_as_float((u & 0x80000000u) ? (u ^ 0x80000000u) : ~u);
}
__device__ __forceinline__ unsigned long long shfl_xor_u64(unsigned long long v, int m) {
  int lo = __shfl_xor((int)(unsigned)v, m);
  int hi = __shfl_xor((int)(unsigned)(v >> 32), m);
  return (((unsigned long long)(unsigned)hi) << 32) | (unsigned)lo;
}

// masks may arrive as int32, uint8, or float32. mask[b][0] is always true
// (num_gt >= 1), which makes the layouts distinguishable.
// Must be called by ALL threads of the block (contains __syncthreads).
__device__ int detect_mask_layout(const void* masks, int* sflag) {
  const unsigned* mw = (const unsigned*)masks;
  if (mw[0] == 0x3f800000u) return 2;   // float32 1.0f
  if (threadIdx.x == 0) *sflag = 0;
  __syncthreads();
  const unsigned char* mb = (const unsigned char*)masks;
  int local = 0;
  for (int i = threadIdx.x; i < BN * GN; i += blockDim.x)
    if ((i & 3) != 0 && mb[i] != 0) local = 1;
  if (local) atomicOr(sflag, 1);
  __syncthreads();
  return (*sflag) ? 1 : 0;
}
__device__ __forceinline__ int mask_val(const void* masks, int layout, int idx) {
  if (layout == 2) return ((const float*)masks)[idx] != 0.0f;
  if (layout == 1) return ((const unsigned char*)masks)[idx] != 0;
  return ((const int*)masks)[idx] != 0;
}

// ---------- K1: zone init + per-block target prep (LDS) + heavy (p,g) loop ----------
__global__ __launch_bounds__(256) void clr_k1(
    const float* __restrict__ preds, const float* __restrict__ targets,
    const void* __restrict__ masks, const int* __restrict__ imw,
    const int* __restrict__ imh, float* __restrict__ ws)
{
  const int b = blockIdx.y, c = blockIdx.x;
  const int tid = threadIdx.x;
  const int lane = tid & 63;
  const int gq = __builtin_amdgcn_readfirstlane(tid >> 6);  // uniform wave id
  const float wf = (float)imw[0];
  const float wm1 = wf - 1.0f, hm1 = (float)imh[0] - 1.0f;

  // ---- zone init (nothing reads these until K2, a later kernel) ----
  {
    int gid = (b * CHN + c) * 256 + tid;
    int* wsi = (int*)ws;
    if (gid < BN * PN) {
      wsi[OFF_CNT + gid] = 0;
      wsi[OFF_SELG + gid] = 0x7fffffff;
      ((unsigned long long*)(ws + OFF_BEST))[gid] = ~0ull;
    }
    if (gid < BN) wsi[OFF_BDONE + gid] = 0;
  }

  // ---- per-block target prep into LDS ----
  __shared__ __align__(16) float sts[GN * NPTSN];
  __shared__ __align__(16) float stw[GN * NPTSN];
  __shared__ float svl[GN], snv[GN], sgx[GN], sgy[GN], sgth[GN];
  __shared__ int sgm[GN];
  __shared__ int sng;
  __shared__ int sflag;
  __shared__ float red[4][3];

  const int mlay = detect_mask_layout(masks, &sflag);

  for (int idx = tid; idx < GN * NPTSN; idx += 256) {
    int g = idx / NPTSN, j = idx - g * NPTSN;
    float t = targets[(size_t)(b * GN + g) * DNN + 6 + j] * wm1;
    sts[idx] = t;
    stw[idx] = (t >= 0.0f && t < wf) ? 1.0f : 0.0f;
  }
  __syncthreads();
  if (tid < GN) {
    float cnt = 0.0f;
    for (int j = 0; j < NPTSN; j++) cnt += stw[tid * NPTSN + j];
    snv[tid] = cnt;               // unclipped (liou)
    svl[tid] = fmaxf(cnt, 1.0f);  // clipped (dist)
    const float* tr = targets + (size_t)(b * GN + tid) * DNN;
    sgx[tid]  = tr[2] * hm1;
    sgy[tid]  = tr[3] * wm1;
    sgth[tid] = tr[4] * 180.0f;
    sgm[tid] = mask_val(masks, mlay, b * GN + tid);
  }
  __syncthreads();
  if (tid == 0) {
    int n = 0;
    for (int g = 0; g < GN; g++) n += sgm[g];
    sng = n;   // mask is a prefix (arange < num_gt)
  }
  __syncthreads();
  const int ng = sng;

  // ---- per-pred load ----
  const int p = c * PPC + lane;
  const bool active = (lane < PPC) && (p < PN);
  float pp[NPTSN];
  float ppx = 0.f, ppy = 0.f, ppth = 0.f;
  if (active) {
    const float* row = preds + (size_t)(b * PN + p) * DNN;
    const float2* r2 = (const float2*)row;     // 8B-aligned (78 floats/row)
    float2 c23 = r2[1], c45 = r2[2];
    ppx = c23.x * hm1; ppy = c23.y * wm1; ppth = c45.x * 180.0f;
    #pragma unroll
    for (int j = 0; j < NPTSN / 2; j++) {
      float2 v = r2[3 + j];
      pp[2 * j]     = v.x * wm1;
      pp[2 * j + 1] = v.y * wm1;
    }
    if (gq == 0) {
      float2 c01 = r2[0];
      float m = fmaxf(c01.x, c01.y);
      float e0 = expf(c01.x - m), e1 = expf(c01.y - m);
      float p1 = fmaxf(e1 / (e0 + e1), EPSF);
      ws[OFF_PX  + b * PN + p] = ppx;
      ws[OFF_PY  + b * PN + p] = ppy;
      ws[OFF_PTH + b * PN + p] = ppth;
      ws[OFF_CLS + b * PN + p] = -logf(p1);
    }
  } else {
    #pragma unroll
    for (int j = 0; j < NPTSN; j++) pp[j] = 0.0f;
  }

  // ---- heavy loop: g interleaved across waves for balance (g = gq + 4i) ----
  float mxd = -INF, mxs = -INF, mxt = -INF;
  for (int i = 0; i < 6; i++) {
    const int g = gq + 4 * i;             // wave-uniform, balanced over masked prefix
    if (g >= ng) break;
    const float NV = snv[g];
    const float4* t4 = (const float4*)&sts[g * NPTSN];  // broadcast ds_read_b128
    float S0 = 0.f, S1 = 0.f, S2 = 0.f, S3 = 0.f;
    if (NV == (float)NPTSN) {
      // fast path: all points valid -> no stw reads, no weight multiply.
      // Bit-exact vs weighted path (elides *1.0f), same accumulation order.
      #pragma unroll
      for (int jj = 0; jj < NPTSN / 4; jj++) {
        float4 t = t4[jj];
        S0 += fabsf(pp[4 * jj + 0] - t.x);
        S1 += fabsf(pp[4 * jj + 1] - t.y);
        S2 += fabsf(pp[4 * jj + 2] - t.z);
        S3 += fabsf(pp[4 * jj + 3] - t.w);
      }
    } else {
      const float4* w4 = (const float4*)&stw[g * NPTSN];
      #pragma unroll
      for (int jj = 0; jj < NPTSN / 4; jj++) {
        float4 t = t4[jj], w = w4[jj];
        S0 += w.x * fabsf(pp[4 * jj + 0] - t.x);
        S1 += w.y * fabsf(pp[4 * jj + 1] - t.y);
        S2 += w.z * fabsf(pp[4 * jj + 2] - t.z);
        S3 += w.w * fabsf(pp[4 * jj + 3] - t.w);
      }
    }
    float S = (S0 + S1) + (S2 + S3);
    const float VL = svl[g];
    float dist = S / VL;
    float liou = (30.0f * NV - S) / (30.0f * NV + S + 1e-9f);
    float dx = ppx - sgx[g], dy = ppy - sgy[g];
    float sd = sqrtf(dx * dx + dy * dy);
    float td = fabsf(ppth - sgth[g]);
    if (active) {
      size_t o = (size_t)(b * GN + g) * PN + p;
      ws[OFF_DIST + o] = dist;
      ws[OFF_LIOU + o] = liou;
      mxd = fmaxf(mxd, dist);
      mxs = fmaxf(mxs, sd);
      mxt = fmaxf(mxt, td);
    }
  }

  #pragma unroll
  for (int off = 32; off; off >>= 1) {
    mxd = fmaxf(mxd, __shfl_xor(mxd, off));
    mxs = fmaxf(mxs, __shfl_xor(mxs, off));
    mxt = fmaxf(mxt, __shfl_xor(mxt, off));
  }
  if (lane == 0) { red[gq][0] = mxd; red[gq][1] = mxs; red[gq][2] = mxt; }
  __syncthreads();
  if (tid == 0) {
    float a = red[0][0], s = red[0][1], t = red[0][2];
    for (int i = 1; i < 4; i++) {
      a = fmaxf(a, red[i][0]);
      s = fmaxf(s, red[i][1]);
      t = fmaxf(t, red[i][2]);
    }
    ws[OFF_PART + (b * CHN + c) * 3 + 0] = a;
    ws[OFF_PART + (b * CHN + c) * 3 + 1] = s;
    ws[OFF_PART + (b * CHN + c) * 3 + 2] = t;
  }
}

// ---------- K2: per (b,g) cost, top-4s, ks, scatter; last arriver per b finalizes ----------
__global__ __launch_bounds__(256) void clr_k2(
    const float* __restrict__ targets, const void* __restrict__ masks,
    const int* __restrict__ imw, const int* __restrict__ imh,
    float* __restrict__ ws, int* __restrict__ out)
{
  const int g = blockIdx.x, b = blockIdx.y;   // grid = (GN, BN)
  const int bg = b * GN + g;
  const int tid = threadIdx.x;
  const int lane = tid & 63;
  const int wv = tid >> 6;
  int* wsi = (int*)ws;
  unsigned long long* bst = (unsigned long long*)(ws + OFF_BEST);

  __shared__ int sflag;
  __shared__ int slast;
  __shared__ unsigned long long ctop[4][4], ltop[4][4];
  const int mlay = detect_mask_layout(masks, &sflag);   // all threads (has barrier)

  // ---- phase B: only masked columns contribute (no early return: arrival below)
  if (mask_val(masks, mlay, bg)) {
    const float hm1 = (float)imh[0] - 1.0f;
    const float wm1 = (float)imw[0] - 1.0f;

    float Md = -INF, Ms = -INF, Mt = -INF;
    for (int c2 = 0; c2 < CHN; c2++) {
      Md = fmaxf(Md, ws[OFF_PART + (b * CHN + c2) * 3 + 0]);
      Ms = fmaxf(Ms, ws[OFF_PART + (b * CHN + c2) * 3 + 1]);
      Mt = fmaxf(Mt, ws[OFF_PART + (b * CHN + c2) * 3 + 2]);
    }
    const float* tr = targets + (size_t)bg * DNN;
    const float tx = tr[2] * hm1, ty = tr[3] * wm1, tth = tr[4] * 180.0f;
    const size_t dbase = (size_t)bg * PN;

    unsigned long long ck[4], lk[4];
    #pragma unroll
    for (int i = 0; i < 4; i++) {
      int p = tid + i * 256;
      unsigned long long kc = ~0ull, kl = ~0ull;
      if (p < PN) {
        float dist = ws[OFF_DIST + dbase + p];
        float liou = ws[OFF_LIOU + dbase + p];
        float px  = ws[OFF_PX  + b * PN + p];
        float py  = ws[OFF_PY  + b * PN + p];
        float pth = ws[OFF_PTH + b * PN + p];
        float cls = ws[OFF_CLS + b * PN + p];
        float dsc = (1.0f - dist / (Md + EPSF)) + 0.01f;
        float dx = px - tx, dy = py - ty;
        float xsc = (1.0f - sqrtf(dx * dx + dy * dy) / (Ms + EPSF)) + 0.01f;
        float tsc = (1.0f - fabsf(pth - tth) / (Mt + EPSF)) + 0.01f;
        float r = (dsc * xsc) * tsc;
        float cost = -(r * r) * 3.0f + cls;
        unsigned oc = ordf(cost);
        kc = (((unsigned long long)oc) << 32) | (unsigned)p;
        kl = (((unsigned long long)(unsigned)(~ordf(liou))) << 32) | (unsigned)p;
        // argmin-over-g for multi-match resolve (first-occurrence tie-break on g)
        atomicMin(&bst[b * PN + p], (((unsigned long long)oc) << 32) | (unsigned)g);
      }
      ck[i] = kc; lk[i] = kl;
    }

    #pragma unroll
    for (int pass = 0; pass < 4; pass++) {
      unsigned long long m = ck[0];
      #pragma unroll
      for (int i = 1; i < 4; i++) m = (ck[i] < m) ? ck[i] : m;
      #pragma unroll
      for (int off = 32; off; off >>= 1) {
        unsigned long long o = shfl_xor_u64(m, off);
        m = (o < m) ? o : m;
      }
      #pragma unroll
      for (int i = 0; i < 4; i++) if (ck[i] == m) ck[i] = ~0ull;
      if (lane == 0) ctop[wv][pass] = m;
    }
    #pragma unroll
    for (int pass = 0; pass < 4; pass++) {
      unsigned long long m = lk[0];
      #pragma unroll
      for (int i = 1; i < 4; i++) m = (lk[i] < m) ? lk[i] : m;
      #pragma unroll
      for (int off = 32; off; off >>= 1) {
        unsigned long long o = shfl_xor_u64(m, off);
        m = (o < m) ? o : m;
      }
      #pragma unroll
      for (int i = 0; i < 4; i++) if (lk[i] == m) lk[i] = ~0ull;
      if (lane == 0) ltop[wv][pass] = m;
    }
    __syncthreads();

    if (tid == 0) {
      unsigned long long c4[4] = {~0ull, ~0ull, ~0ull, ~0ull};
      unsigned long long l4[4] = {~0ull, ~0ull, ~0ull, ~0ull};
      for (int i = 0; i < 16; i++) {
        unsigned long long v = ctop[i >> 2][i & 3];
        for (int j = 0; j < 4; j++)
          if (v < c4[j]) { unsigned long long t = c4[j]; c4[j] = v; v = t; }
        v = ltop[i >> 2][i & 3];
        for (int j = 0; j < 4; j++)
          if (v < l4[j]) { unsigned long long t = l4[j]; l4[j] = v; v = t; }
      }
      // l4 ascending keys == liou descending values; sum in that order like top_k
      float s = 0.0f;
      for (int j = 0; j < 4; j++) s += unordf(~(unsigned)(l4[j] >> 32));
      int k = (int)s;                 // trunc toward zero == astype(int32)
      if (k < 1) k = 1;
      if (k > 4) k = 4;
      for (int j = 0; j < k; j++) {
        int cand = (int)(unsigned)(c4[j] & 0xffffffffu);
        atomicAdd(&wsi[OFF_CNT + b * PN + cand], 1);
        atomicMin(&wsi[OFF_SELG + b * PN + cand], g);
      }
    }
  }

  // ---- arrival: classic threadfence-reduction pattern (no spinning) ----
  __threadfence();               // each thread: device-order its atomics before barrier
  __syncthreads();               // ...before tid0 signals arrival
  if (tid == 0) slast = atomicAdd(&wsi[OFF_BDONE + b], 1);
  __syncthreads();

  // ---- last arriver for this b finalizes its 1000 outputs ----
  // CNT/SELG/BEST were all written via device-scope atomics; re-read them via
  // agent-scope atomic loads (coherent point) -- plain loads could hit stale L1/L2.
  if (slast == GN - 1) {
    __threadfence();
    for (int p = tid; p < PN; p += 256) {
      const int i = b * PN + p;
      int cnt = __hip_atomic_load(&wsi[OFF_CNT + i], __ATOMIC_RELAXED,
                                  __HIP_MEMORY_SCOPE_AGENT);
      int matched = -1;
      if (cnt == 1) {
        matched = __hip_atomic_load(&wsi[OFF_SELG + i], __ATOMIC_RELAXED,
                                    __HIP_MEMORY_SCOPE_AGENT);
      } else if (cnt > 1) {
        unsigned long long bv = __hip_atomic_load(&bst[i], __ATOMIC_RELAXED,
                                                  __HIP_MEMORY_SCOPE_AGENT);
        matched = (int)(unsigned)(bv & 0xffffffffull);
      }
      out[i] = (cnt > 0) ? 1 : 0;
      out[BN * PN + i] = matched;
    }
  }
}

extern "C" void kernel_launch(void* const* d_in, const int* in_sizes, int n_in,
                              void* d_out, int out_size, void* d_ws, size_t ws_size,
                              hipStream_t stream) {
  const float* preds   = (const float*)d_in[0];
  const float* targets = (const float*)d_in[1];
  const void*  masks   = (const void*)d_in[2];
  const int*   imw     = (const int*)d_in[3];
  const int*   imh     = (const int*)d_in[4];
  float* ws = (float*)d_ws;
  int*   out = (int*)d_out;

  hipLaunchKernelGGL(clr_k1, dim3(CHN, BN), dim3(256), 0, stream,
                     preds, targets, masks, imw, imh, ws);
  hipLaunchKernelGGL(clr_k2, dim3(GN, BN), dim3(256), 0, stream,
                     targets, masks, imw, imh, ws, out);
}

// Round 4
// 96.006 us; speedup vs baseline: 2.2790x; 1.5866x over previous
//
#include <hip/hip_runtime.h>
#include <cstdint>
#include <cstddef>

#define BN 32
#define PN 1000
#define GN 24
#define NPTSN 72
#define DNN 78
#define CHN 16         // pred chunks in K1
#define PPC 63         // preds per chunk (16*63 >= 1000)
#define EPSF 1e-8f
#define INF __builtin_inff()

// ---- workspace layout (units of 4 bytes) ----
#define OFF_DIST  0
#define OFF_LIOU  768000
#define OFF_PX    1536000
#define OFF_PY    1568000
#define OFF_PTH   1600000
#define OFF_CLS   1632000
#define OFF_PART  1664000   // partial maxima [b][16][3]
#define OFF_CNT   1665536   // match count (int)   [b][p]
#define OFF_SELG  1697536   // unique selector g   [b][p]
#define OFF_BEST  1729536   // u64 (ordcost<<32|g) [b][p]  (even -> 8B aligned)
#define OFF_BDONE 1793536   // per-b arrival counter [b]
// total ~1.79M floats = 7.2 MB (ws is 256 MB)

// ---------- helpers ----------
__device__ __forceinline__ unsigned ordf(float f) {
  unsigned u = __float_as_uint(f);
  return (u & 0x80000000u) ? ~u : (u | 0x80000000u);
}
__device__ __forceinline__ float unordf(unsigned u) {
  return __uint_as_float((u & 0x80000000u) ? (u ^ 0x80000000u) : ~u);
}
__device__ __forceinline__ unsigned long long shfl_xor_u64(unsigned long long v, int m) {
  int lo = __shfl_xor((int)(unsigned)v, m);
  int hi = __shfl_xor((int)(unsigned)(v >> 32), m);
  return (((unsigned long long)(unsigned)hi) << 32) | (unsigned)lo;
}

// masks may arrive as int32, uint8, or float32. mask[b][0] is always true
// (num_gt >= 1), which makes the layouts distinguishable.
// Must be called by ALL threads of the block (contains __syncthreads).
__device__ int detect_mask_layout(const void* masks, int* sflag) {
  const unsigned* mw = (const unsigned*)masks;
  if (mw[0] == 0x3f800000u) return 2;   // float32 1.0f
  if (threadIdx.x == 0) *sflag = 0;
  __syncthreads();
  const unsigned char* mb = (const unsigned char*)masks;
  int local = 0;
  for (int i = threadIdx.x; i < BN * GN; i += blockDim.x)
    if ((i & 3) != 0 && mb[i] != 0) local = 1;
  if (local) atomicOr(sflag, 1);
  __syncthreads();
  return (*sflag) ? 1 : 0;
}
__device__ __forceinline__ int mask_val(const void* masks, int layout, int idx) {
  if (layout == 2) return ((const float*)masks)[idx] != 0.0f;
  if (layout == 1) return ((const unsigned char*)masks)[idx] != 0;
  return ((const int*)masks)[idx] != 0;
}

// ---------- K1: zone init + per-block target prep (LDS) + heavy (p,g) loop ----------
__global__ __launch_bounds__(256) void clr_k1(
    const float* __restrict__ preds, const float* __restrict__ targets,
    const void* __restrict__ masks, const int* __restrict__ imw,
    const int* __restrict__ imh, float* __restrict__ ws)
{
  const int b = blockIdx.y, c = blockIdx.x;
  const int tid = threadIdx.x;
  const int lane = tid & 63;
  const int gq = __builtin_amdgcn_readfirstlane(tid >> 6);  // uniform wave id
  const float wf = (float)imw[0];
  const float wm1 = wf - 1.0f, hm1 = (float)imh[0] - 1.0f;

  // ---- zone init (nothing reads these until K2, a later kernel) ----
  {
    int gid = (b * CHN + c) * 256 + tid;
    int* wsi = (int*)ws;
    if (gid < BN * PN) {
      wsi[OFF_CNT + gid] = 0;
      wsi[OFF_SELG + gid] = 0x7fffffff;
      ((unsigned long long*)(ws + OFF_BEST))[gid] = ~0ull;
    }
    if (gid < BN) wsi[OFF_BDONE + gid] = 0;
  }

  // ---- per-block target prep into LDS (sts only; validity derived from it) ----
  __shared__ __align__(16) float sts[GN * NPTSN];
  __shared__ float svl[GN], snv[GN], sgx[GN], sgy[GN], sgth[GN];
  __shared__ int sgm[GN];
  __shared__ int sng;
  __shared__ int sflag;
  __shared__ float red[4][3];

  const int mlay = detect_mask_layout(masks, &sflag);

  for (int idx = tid; idx < GN * NPTSN; idx += 256) {
    int g = idx / NPTSN, j = idx - g * NPTSN;
    sts[idx] = targets[(size_t)(b * GN + g) * DNN + 6 + j] * wm1;
  }
  __syncthreads();
  if (tid < GN) {
    float cnt = 0.0f;
    for (int j = 0; j < NPTSN; j++) {
      float t = sts[tid * NPTSN + j];
      cnt += (t >= 0.0f && t < wf) ? 1.0f : 0.0f;
    }
    snv[tid] = cnt;               // unclipped (liou)
    svl[tid] = fmaxf(cnt, 1.0f);  // clipped (dist)
    const float* tr = targets + (size_t)(b * GN + tid) * DNN;
    sgx[tid]  = tr[2] * hm1;
    sgy[tid]  = tr[3] * wm1;
    sgth[tid] = tr[4] * 180.0f;
    sgm[tid] = mask_val(masks, mlay, b * GN + tid);
  }
  __syncthreads();
  if (tid == 0) {
    int n = 0;
    for (int g = 0; g < GN; g++) n += sgm[g];
    sng = n;   // mask is a prefix (arange < num_gt)
  }
  __syncthreads();
  const int ng = sng;

  // ---- per-pred load ----
  const int p = c * PPC + lane;
  const bool active = (lane < PPC) && (p < PN);
  float pp[NPTSN];
  float ppx = 0.f, ppy = 0.f, ppth = 0.f;
  if (active) {
    const float* row = preds + (size_t)(b * PN + p) * DNN;
    const float2* r2 = (const float2*)row;     // 8B-aligned (78 floats/row)
    float2 c23 = r2[1], c45 = r2[2];
    ppx = c23.x * hm1; ppy = c23.y * wm1; ppth = c45.x * 180.0f;
    #pragma unroll
    for (int j = 0; j < NPTSN / 2; j++) {
      float2 v = r2[3 + j];
      pp[2 * j]     = v.x * wm1;
      pp[2 * j + 1] = v.y * wm1;
    }
    if (gq == 0) {
      float2 c01 = r2[0];
      float m = fmaxf(c01.x, c01.y);
      float e0 = expf(c01.x - m), e1 = expf(c01.y - m);
      float p1 = fmaxf(e1 / (e0 + e1), EPSF);
      ws[OFF_PX  + b * PN + p] = ppx;
      ws[OFF_PY  + b * PN + p] = ppy;
      ws[OFF_PTH + b * PN + p] = ppth;
      ws[OFF_CLS + b * PN + p] = -logf(p1);
    }
  } else {
    #pragma unroll
    for (int j = 0; j < NPTSN; j++) pp[j] = 0.0f;
  }

  // ---- heavy loop: g interleaved across waves for balance (g = gq + 4i) ----
  float mxd = -INF, mxs = -INF, mxt = -INF;
  for (int i = 0; i < 6; i++) {
    const int g = gq + 4 * i;             // wave-uniform, balanced over masked prefix
    if (g >= ng) break;
    const float NV = snv[g];
    const float4* t4 = (const float4*)&sts[g * NPTSN];  // broadcast ds_read_b128
    float S0 = 0.f, S1 = 0.f, S2 = 0.f, S3 = 0.f;
    if (NV == (float)NPTSN) {
      // fast path: all points valid -> no weight reads, no weight multiply.
      // Bit-exact vs weighted path (elides *1.0f), same accumulation order.
      #pragma unroll
      for (int jj = 0; jj < NPTSN / 4; jj++) {
        float4 t = t4[jj];
        S0 += fabsf(pp[4 * jj + 0] - t.x);
        S1 += fabsf(pp[4 * jj + 1] - t.y);
        S2 += fabsf(pp[4 * jj + 2] - t.z);
        S3 += fabsf(pp[4 * jj + 3] - t.w);
      }
    } else {
      // general path: weight = validity predicate on the scaled target value
      #pragma unroll
      for (int jj = 0; jj < NPTSN / 4; jj++) {
        float4 t = t4[jj];
        float wx = (t.x >= 0.0f && t.x < wf) ? 1.0f : 0.0f;
        float wy = (t.y >= 0.0f && t.y < wf) ? 1.0f : 0.0f;
        float wz = (t.z >= 0.0f && t.z < wf) ? 1.0f : 0.0f;
        float ww = (t.w >= 0.0f && t.w < wf) ? 1.0f : 0.0f;
        S0 += wx * fabsf(pp[4 * jj + 0] - t.x);
        S1 += wy * fabsf(pp[4 * jj + 1] - t.y);
        S2 += wz * fabsf(pp[4 * jj + 2] - t.z);
        S3 += ww * fabsf(pp[4 * jj + 3] - t.w);
      }
    }
    float S = (S0 + S1) + (S2 + S3);
    const float VL = svl[g];
    float dist = S / VL;
    float liou = (30.0f * NV - S) / (30.0f * NV + S + 1e-9f);
    float dx = ppx - sgx[g], dy = ppy - sgy[g];
    float sd = sqrtf(dx * dx + dy * dy);
    float td = fabsf(ppth - sgth[g]);
    if (active) {
      size_t o = (size_t)(b * GN + g) * PN + p;
      ws[OFF_DIST + o] = dist;
      ws[OFF_LIOU + o] = liou;
      mxd = fmaxf(mxd, dist);
      mxs = fmaxf(mxs, sd);
      mxt = fmaxf(mxt, td);
    }
  }

  #pragma unroll
  for (int off = 32; off; off >>= 1) {
    mxd = fmaxf(mxd, __shfl_xor(mxd, off));
    mxs = fmaxf(mxs, __shfl_xor(mxs, off));
    mxt = fmaxf(mxt, __shfl_xor(mxt, off));
  }
  if (lane == 0) { red[gq][0] = mxd; red[gq][1] = mxs; red[gq][2] = mxt; }
  __syncthreads();
  if (tid == 0) {
    float a = red[0][0], s = red[0][1], t = red[0][2];
    for (int i = 1; i < 4; i++) {
      a = fmaxf(a, red[i][0]);
      s = fmaxf(s, red[i][1]);
      t = fmaxf(t, red[i][2]);
    }
    ws[OFF_PART + (b * CHN + c) * 3 + 0] = a;
    ws[OFF_PART + (b * CHN + c) * 3 + 1] = s;
    ws[OFF_PART + (b * CHN + c) * 3 + 2] = t;
  }
}

// ---------- K2: per (b,g) cost, top-4s, ks, scatter; last arriver per b finalizes ----------
// Cross-block state (CNT/SELG/BEST/BDONE) is written EXCLUSIVELY via device-scope
// atomics (coherent at the MALL per-op). NO __threadfence(): on gfx950 an
// agent-scope fence emits whole-L2 writeback/invalidate -- measured ~80us across
// 768 blocks (round 3). Ordering instead: __syncthreads() drains vmcnt(0) (compiler
// emits s_waitcnt vmcnt(0) lgkmcnt(0) before s_barrier), so every block's scatter
// atomics are globally complete before its arrival atomicAdd issues. The finalizer
// re-reads via RELAXED agent-scope atomic loads (read at the coherent point).
__global__ __launch_bounds__(256) void clr_k2(
    const float* __restrict__ targets, const void* __restrict__ masks,
    const int* __restrict__ imw, const int* __restrict__ imh,
    float* __restrict__ ws, int* __restrict__ out)
{
  const int g = blockIdx.x, b = blockIdx.y;   // grid = (GN, BN)
  const int bg = b * GN + g;
  const int tid = threadIdx.x;
  const int lane = tid & 63;
  const int wv = tid >> 6;
  int* wsi = (int*)ws;
  unsigned long long* bst = (unsigned long long*)(ws + OFF_BEST);

  __shared__ int sflag;
  __shared__ int slast;
  __shared__ unsigned long long ctop[4][4], ltop[4][4];
  const int mlay = detect_mask_layout(masks, &sflag);   // all threads (has barrier)

  // ---- phase B: only masked columns contribute (no early return: arrival below)
  if (mask_val(masks, mlay, bg)) {
    const float hm1 = (float)imh[0] - 1.0f;
    const float wm1 = (float)imw[0] - 1.0f;

    float Md = -INF, Ms = -INF, Mt = -INF;
    for (int c2 = 0; c2 < CHN; c2++) {
      Md = fmaxf(Md, ws[OFF_PART + (b * CHN + c2) * 3 + 0]);
      Ms = fmaxf(Ms, ws[OFF_PART + (b * CHN + c2) * 3 + 1]);
      Mt = fmaxf(Mt, ws[OFF_PART + (b * CHN + c2) * 3 + 2]);
    }
    const float* tr = targets + (size_t)bg * DNN;
    const float tx = tr[2] * hm1, ty = tr[3] * wm1, tth = tr[4] * 180.0f;
    const size_t dbase = (size_t)bg * PN;

    unsigned long long ck[4], lk[4];
    #pragma unroll
    for (int i = 0; i < 4; i++) {
      int p = tid + i * 256;
      unsigned long long kc = ~0ull, kl = ~0ull;
      if (p < PN) {
        float dist = ws[OFF_DIST + dbase + p];
        float liou = ws[OFF_LIOU + dbase + p];
        float px  = ws[OFF_PX  + b * PN + p];
        float py  = ws[OFF_PY  + b * PN + p];
        float pth = ws[OFF_PTH + b * PN + p];
        float cls = ws[OFF_CLS + b * PN + p];
        float dsc = (1.0f - dist / (Md + EPSF)) + 0.01f;
        float dx = px - tx, dy = py - ty;
        float xsc = (1.0f - sqrtf(dx * dx + dy * dy) / (Ms + EPSF)) + 0.01f;
        float tsc = (1.0f - fabsf(pth - tth) / (Mt + EPSF)) + 0.01f;
        float r = (dsc * xsc) * tsc;
        float cost = -(r * r) * 3.0f + cls;
        unsigned oc = ordf(cost);
        kc = (((unsigned long long)oc) << 32) | (unsigned)p;
        kl = (((unsigned long long)(unsigned)(~ordf(liou))) << 32) | (unsigned)p;
        // argmin-over-g for multi-match resolve (first-occurrence tie-break on g)
        atomicMin(&bst[b * PN + p], (((unsigned long long)oc) << 32) | (unsigned)g);
      }
      ck[i] = kc; lk[i] = kl;
    }

    #pragma unroll
    for (int pass = 0; pass < 4; pass++) {
      unsigned long long m = ck[0];
      #pragma unroll
      for (int i = 1; i < 4; i++) m = (ck[i] < m) ? ck[i] : m;
      #pragma unroll
      for (int off = 32; off; off >>= 1) {
        unsigned long long o = shfl_xor_u64(m, off);
        m = (o < m) ? o : m;
      }
      #pragma unroll
      for (int i = 0; i < 4; i++) if (ck[i] == m) ck[i] = ~0ull;
      if (lane == 0) ctop[wv][pass] = m;
    }
    #pragma unroll
    for (int pass = 0; pass < 4; pass++) {
      unsigned long long m = lk[0];
      #pragma unroll
      for (int i = 1; i < 4; i++) m = (lk[i] < m) ? lk[i] : m;
      #pragma unroll
      for (int off = 32; off; off >>= 1) {
        unsigned long long o = shfl_xor_u64(m, off);
        m = (o < m) ? o : m;
      }
      #pragma unroll
      for (int i = 0; i < 4; i++) if (lk[i] == m) lk[i] = ~0ull;
      if (lane == 0) ltop[wv][pass] = m;
    }
    __syncthreads();

    if (tid == 0) {
      unsigned long long c4[4] = {~0ull, ~0ull, ~0ull, ~0ull};
      unsigned long long l4[4] = {~0ull, ~0ull, ~0ull, ~0ull};
      for (int i = 0; i < 16; i++) {
        unsigned long long v = ctop[i >> 2][i & 3];
        for (int j = 0; j < 4; j++)
          if (v < c4[j]) { unsigned long long t = c4[j]; c4[j] = v; v = t; }
        v = ltop[i >> 2][i & 3];
        for (int j = 0; j < 4; j++)
          if (v < l4[j]) { unsigned long long t = l4[j]; l4[j] = v; v = t; }
      }
      // l4 ascending keys == liou descending values; sum in that order like top_k
      float s = 0.0f;
      for (int j = 0; j < 4; j++) s += unordf(~(unsigned)(l4[j] >> 32));
      int k = (int)s;                 // trunc toward zero == astype(int32)
      if (k < 1) k = 1;
      if (k > 4) k = 4;
      for (int j = 0; j < k; j++) {
        int cand = (int)(unsigned)(c4[j] & 0xffffffffu);
        atomicAdd(&wsi[OFF_CNT + b * PN + cand], 1);
        atomicMin(&wsi[OFF_SELG + b * PN + cand], g);
      }
    }
  }

  // ---- arrival (fence-free): barrier drains vmcnt -> scatter atomics complete ----
  __syncthreads();
  if (tid == 0) {
    asm volatile("s_waitcnt vmcnt(0)" ::: "memory");   // paranoia; already drained
    slast = atomicAdd(&wsi[OFF_BDONE + b], 1);
  }
  __syncthreads();

  // ---- last arriver for this b finalizes its 1000 outputs ----
  if (slast == GN - 1) {
    for (int p = tid; p < PN; p += 256) {
      const int i = b * PN + p;
      int cnt = __hip_atomic_load(&wsi[OFF_CNT + i], __ATOMIC_RELAXED,
                                  __HIP_MEMORY_SCOPE_AGENT);
      int matched = -1;
      if (cnt == 1) {
        matched = __hip_atomic_load(&wsi[OFF_SELG + i], __ATOMIC_RELAXED,
                                    __HIP_MEMORY_SCOPE_AGENT);
      } else if (cnt > 1) {
        unsigned long long bv = __hip_atomic_load(&bst[i], __ATOMIC_RELAXED,
                                                  __HIP_MEMORY_SCOPE_AGENT);
        matched = (int)(unsigned)(bv & 0xffffffffull);
      }
      out[i] = (cnt > 0) ? 1 : 0;
      out[BN * PN + i] = matched;
    }
  }
}

extern "C" void kernel_launch(void* const* d_in, const int* in_sizes, int n_in,
                              void* d_out, int out_size, void* d_ws, size_t ws_size,
                              hipStream_t stream) {
  const float* preds   = (const float*)d_in[0];
  const float* targets = (const float*)d_in[1];
  const void*  masks   = (const void*)d_in[2];
  const int*   imw     = (const int*)d_in[3];
  const int*   imh     = (const int*)d_in[4];
  float* ws = (float*)d_ws;
  int*   out = (int*)d_out;

  hipLaunchKernelGGL(clr_k1, dim3(CHN, BN), dim3(256), 0, stream,
                     preds, targets, masks, imw, imh, ws);
  hipLaunchKernelGGL(clr_k2, dim3(GN, BN), dim3(256), 0, stream,
                     targets, masks, imw, imh, ws, out);
}